// Round 21
// baseline (113.634 us; speedup 1.0000x reference)
//
#include <hip/hip_runtime.h>

#define S_LEN 4096
#define BATCH 2
#define DIM 64
#define RAD 128
#define NPOS 257
#define KEXT 4416              // 4096 + 5*64 (rel rows padded); KEXT/16 = 276 tiles
#define NKT 276                // K fragment tiles per batch
#define QREL_STR 260
#define PSTR 72                // P LDS row stride in u16 (144B, 16B-aligned)

typedef short s16x8 __attribute__((ext_vector_type(8)));
typedef short s16x4 __attribute__((ext_vector_type(4)));
typedef float f32x4 __attribute__((ext_vector_type(4)));
typedef unsigned short u16;
typedef unsigned int u32;

__device__ __forceinline__ u16 f2bf(float f) {
  union { float f; u32 u; } v; v.f = f;
  u32 u = v.u;
  return (u16)((u + 0x7FFFu + ((u >> 16) & 1u)) >> 16);  // RNE
}
__device__ __forceinline__ float bf2f(u16 h) {
  union { u32 u; float f; } v; v.u = ((u32)h) << 16; return v.f;
}

// KF[b][Ti][ks][lane][j]: fragment-contiguous K (+rel rows appended).
__global__ void prep_k2(const float* __restrict__ K, const float* __restrict__ rel,
                        u16* __restrict__ KF) {
  __shared__ float lds[16][65];
  const int b = blockIdx.y;
  const int Ti = blockIdx.x;           // 0..275
  const int tid = threadIdx.x;         // 128
  for (int i = tid; i < 1024; i += 128) {
    const int r = i >> 6, c = i & 63;
    const int t = Ti * 16 + r;
    float v = 0.f;
    if (t < S_LEN) v = K[((size_t)b * S_LEN + t) * DIM + c];
    else if (t - S_LEN < NPOS) v = rel[(size_t)(t - S_LEN) * DIM + c];
    lds[r][c] = v;
  }
  __syncthreads();
  const int ks = tid >> 6, lane = tid & 63;
  const int l15 = lane & 15, q4 = lane >> 4;
  s16x8 o;
#pragma unroll
  for (int j = 0; j < 8; ++j) o[j] = (short)f2bf(lds[l15][ks * 32 + q4 * 8 + j]);
  *reinterpret_cast<s16x8*>(KF + (((size_t)(b * NKT + Ti)) * 2 + ks) * 512 + lane * 8) = o;
}

// VF[b][T6][ks][dn][lane][j]: fragment-contiguous V.
__global__ void prep_v2(const float* __restrict__ V, u16* __restrict__ VF) {
  __shared__ float lds[64][65];
  const int b = blockIdx.y;
  const int T6 = blockIdx.x;           // 0..63
  const int tid = threadIdx.x;         // 256
  for (int i = tid; i < 4096; i += 256) {
    const int r = i >> 6, c = i & 63;
    lds[r][c] = V[((size_t)b * S_LEN + T6 * 64 + r) * DIM + c];
  }
  __syncthreads();
  const int dn = tid >> 6, lane = tid & 63;
  const int l15 = lane & 15, q4 = lane >> 4;
#pragma unroll
  for (int ks = 0; ks < 2; ++ks) {
    s16x8 o;
#pragma unroll
    for (int j = 0; j < 8; ++j) o[j] = (short)f2bf(lds[ks * 32 + q4 * 8 + j][dn * 16 + l15]);
    *reinterpret_cast<s16x8*>(
        VF + ((((size_t)(b * 64 + T6)) * 2 + ks) * 4 + dn) * 512 + lane * 8) = o;
  }
}

// R16/R20 structure. NOSTORE=0,reps=1 -> the proven 49.2us kernel (real output).
// NOSTORE=1 -> decision probe: entire energy-store path (estage write +
// transposed read + nt stores) deleted; e stays live via exp->P->Z (rule #17);
// reps>1 with opaque per-rep pointer offset so loads re-issue each rep.
// Swapped-operand MFMAs keep q == l15 lane-local:
//   QK^T: mfma(kf, qf) -> D[t=q4*4+reg][q=l15]
//   PV:   mfma(vf, pf) -> D[d=dn*16+q4*4+reg][q=l15]
template <int NOSTORE>
__launch_bounds__(512, 4)
__global__ void attn_main(const float* __restrict__ Q,
                          const u16* __restrict__ KF,
                          const u16* __restrict__ VF,
                          float* __restrict__ energy,
                          float* __restrict__ Zout,
                          int reps) {
  // carve: qrel_bf[16*260] u16 (8320B) | estage 8x4096B (32768B) | plds (18432B)
  __shared__ __align__(16) char smem[8320 + 32768 + 18432];
  u16* qrel_bf = (u16*)smem;
  char* estage = smem + 8320;
  u16* plds = (u16*)(smem + 8320 + 32768);
  float* Zbuf = (float*)estage;        // epilogue overlay

  const int tid = threadIdx.x;
  const int lane = tid & 63;
  const int wid = tid >> 6;            // 0..7
  const int l15 = lane & 15, q4 = lane >> 4;
  const int bx = blockIdx.x;
  const int b = bx >> 8;
  const int s0 = (bx & 255) * 16;

  const u16* KFB = KF + (size_t)b * NKT * 2 * 512;
  const u16* VFB = VF + (size_t)b * 64 * 2 * 4 * 512;
  const int lane8 = lane * 8;
  char* esw = estage + wid * 4096;

  // ---- Q B-fragments (row s0+l15) ----
  s16x8 qfrag[2];
  {
    const float* qp = Q + ((size_t)b * S_LEN + s0 + l15) * DIM + q4 * 8;
#pragma unroll
    for (int ks = 0; ks < 2; ++ks) {
      f32x4 a = *reinterpret_cast<const f32x4*>(qp + ks * 32);
      f32x4 c = *reinterpret_cast<const f32x4*>(qp + ks * 32 + 4);
      s16x8 f;
#pragma unroll
      for (int j = 0; j < 4; ++j) { f[j] = (short)f2bf(a[j]); f[4 + j] = (short)f2bf(c[j]); }
      qfrag[ks] = f;
    }
  }

  // ---- prologue: Q_rel[p][q] via mfma(rel_frag, q); waves 0..4 ----
  for (int pt = wid; pt < 5; pt += 8) {
    f32x4 acc[4] = {};
#pragma unroll
    for (int ks = 0; ks < 2; ++ks)
#pragma unroll
      for (int nf = 0; nf < 4; ++nf) {
        s16x8 kf = *reinterpret_cast<const s16x8*>(
            KFB + ((size_t)(256 + pt * 4 + nf) * 2 + ks) * 512 + lane8);
        acc[nf] = __builtin_amdgcn_mfma_f32_16x16x32_bf16(kf, qfrag[ks], acc[nf], 0, 0, 0);
      }
#pragma unroll
    for (int nf = 0; nf < 4; ++nf)
#pragma unroll
      for (int reg = 0; reg < 4; ++reg) {
        int p = pt * 64 + nf * 16 + q4 * 4 + reg;
        if (p < NPOS) qrel_bf[l15 * QREL_STR + p] = f2bf(acc[nf][reg]);
      }
  }
  __syncthreads();

  // per-row clamped-rel constants, pre-scaled by 1/8
  const float c8lo = bf2f(qrel_bf[l15 * QREL_STR + 0]) * 0.125f;
  const float c8hi = bf2f(qrel_bf[l15 * QREL_STR + 256]) * 0.125f;

  // ---- main loop: 8 t-tiles of 64 per wave, barrier-free ----
  const int qglob = s0 + l15;
  const int qoff = l15 * QREL_STR + RAD;
  u16* pw = plds + wid * 16 * PSTR;
  float* eblk = energy + ((size_t)b * S_LEN + s0) * S_LEN;
  const int hi = lane >> 4, m16 = lane & 15;

  float mprev = -INFINITY, lsum = 0.f;
  f32x4 zacc[4] = {};

  for (int rep = 0; rep < reps; ++rep) {
    int zoff = 0;
    if constexpr (NOSTORE)
      asm("v_and_b32 %0, 0, %1" : "=v"(zoff) : "v"(rep));  // opaque 0, defeats CSE
    const u16* KFR = KFB + zoff;
    const u16* VFR = VFB + zoff;

    for (int it = 0; it < 8; ++it) {
      const int t0 = wid * 512 + it * 64;
      const int ti4 = t0 >> 4;
      const int t6 = t0 >> 6;

      // QK^T from fragment-contiguous KF
      f32x4 acc[4] = {};
#pragma unroll
      for (int ks = 0; ks < 2; ++ks)
#pragma unroll
        for (int nf = 0; nf < 4; ++nf) {
          s16x8 kf = *reinterpret_cast<const s16x8*>(
              KFR + ((size_t)(ti4 + nf) * 2 + ks) * 512 + lane8);
          acc[nf] = __builtin_amdgcn_mfma_f32_16x16x32_bf16(kf, qfrag[ks], acc[nf], 0, 0, 0);
        }

      // V fragments issued early; latency hides under softmax
      s16x8 vf[2][4];
#pragma unroll
      for (int ks = 0; ks < 2; ++ks)
#pragma unroll
        for (int dn = 0; dn < 4; ++dn)
          vf[ks][dn] = *reinterpret_cast<const s16x8*>(
              VFR + (((size_t)t6 * 2 + ks) * 4 + dn) * 512 + lane8);

      // rel shift + scale (band-split), lane max
      float mloc = -INFINITY;
      if (t0 >= s0 + 143) {
#pragma unroll
        for (int nf = 0; nf < 4; ++nf)
#pragma unroll
          for (int reg = 0; reg < 4; ++reg) {
            float e = fmaf(acc[nf][reg], 0.125f, c8hi);
            acc[nf][reg] = e;
            mloc = fmaxf(mloc, e);
          }
      } else if (t0 <= s0 - 191) {
#pragma unroll
        for (int nf = 0; nf < 4; ++nf)
#pragma unroll
          for (int reg = 0; reg < 4; ++reg) {
            float e = fmaf(acc[nf][reg], 0.125f, c8lo);
            acc[nf][reg] = e;
            mloc = fmaxf(mloc, e);
          }
      } else {
#pragma unroll
        for (int nf = 0; nf < 4; ++nf) {
          const int tb = t0 + nf * 16 + q4 * 4;
#pragma unroll
          for (int reg = 0; reg < 4; ++reg) {
            int p = tb + reg - qglob;
            p = (p < -RAD) ? -RAD : (p > RAD ? RAD : p);
            float e = (acc[nf][reg] + bf2f(qrel_bf[qoff + p])) * 0.125f;
            acc[nf][reg] = e;
            mloc = fmaxf(mloc, e);
          }
        }
      }

      if constexpr (!NOSTORE) {
        // stage e-tile into private LDS (swizzled; read side applies same XOR)
#pragma unroll
        for (int nf = 0; nf < 4; ++nf) {
          int off = ((l15 >> 2) << 10) + ((l15 & 3) << 8) + ((nf * 4 + q4) << 4);
          off ^= (l15 & 7) << 4;
          *reinterpret_cast<f32x4*>(esw + off) = acc[nf];
        }
      }

      // online softmax; skip rescale when max didn't grow
      if (__all(mloc <= mprev)) {
      } else {
        mloc = fmaxf(mloc, __shfl_xor(mloc, 16));
        mloc = fmaxf(mloc, __shfl_xor(mloc, 32));
        const float mn = fmaxf(mprev, mloc);
        const float alpha = __expf(mprev - mn);
        mprev = mn;
        lsum *= alpha;
#pragma unroll
        for (int dn = 0; dn < 4; ++dn) zacc[dn] *= alpha;
      }

      float rs = 0.f;
#pragma unroll
      for (int nf = 0; nf < 4; ++nf) {
        float p0 = __expf(acc[nf][0] - mprev);
        float p1 = __expf(acc[nf][1] - mprev);
        float p2 = __expf(acc[nf][2] - mprev);
        float p3 = __expf(acc[nf][3] - mprev);
        rs += (p0 + p1) + (p2 + p3);
        union { u32 w[2]; s16x4 v; } pk;
        asm("v_cvt_pk_bf16_f32 %0, %1, %2" : "=v"(pk.w[0]) : "v"(p0), "v"(p1));
        asm("v_cvt_pk_bf16_f32 %0, %1, %2" : "=v"(pk.w[1]) : "v"(p2), "v"(p3));
        *reinterpret_cast<s16x4*>(pw + l15 * PSTR + nf * 16 + q4 * 4) = pk.v;
      }
      rs += __shfl_xor(rs, 16);
      rs += __shfl_xor(rs, 32);
      lsum += rs;

      // PV: mfma(vf, pf) -> zacc[dn] holds Z[d=dn*16+q4*4+reg][q=l15]
#pragma unroll
      for (int ks = 0; ks < 2; ++ks) {
        s16x8 pf = *reinterpret_cast<const s16x8*>(pw + l15 * PSTR + ks * 32 + q4 * 8);
#pragma unroll
        for (int dn = 0; dn < 4; ++dn)
          zacc[dn] = __builtin_amdgcn_mfma_f32_16x16x32_bf16(vf[ks][dn], pf, zacc[dn], 0, 0, 0);
      }

      if constexpr (!NOSTORE) {
        // FULL-LINE energy store: read e-tile transposed from LDS, 4 rows x 256B
#pragma unroll
        for (int j = 0; j < 4; ++j) {
          const int r = j * 4 + hi;
          int off = (j << 10) + (hi << 8) + (m16 << 4);
          off ^= (r & 7) << 4;
          f32x4 v = *reinterpret_cast<const f32x4*>(esw + off);
          __builtin_nontemporal_store(
              v, reinterpret_cast<f32x4*>(eblk + (size_t)r * S_LEN + t0 + m16 * 4));
        }
      }
    }
  }

  // ---- cross-wave combine (overlay Zbuf on estage+plds) ----
  __syncthreads();
#pragma unroll
  for (int dn = 0; dn < 4; ++dn)
    *reinterpret_cast<f32x4*>(&Zbuf[(wid * 16 + l15) * 64 + dn * 16 + q4 * 4]) = zacc[dn];
  if (q4 == 0) {
    Zbuf[8192 + wid * 16 + l15] = mprev;
    Zbuf[8320 + wid * 16 + l15] = lsum;
  }
  __syncthreads();

  {
    const int r0 = tid >> 6, d = tid & 63;
#pragma unroll
    for (int rr = 0; rr < 2; ++rr) {
      const int r = rr * 8 + r0;
      float mf = -INFINITY;
#pragma unroll
      for (int w = 0; w < 8; ++w) mf = fmaxf(mf, Zbuf[8192 + w * 16 + r]);
      float lf = 0.f, z = 0.f;
#pragma unroll
      for (int w = 0; w < 8; ++w) {
        const float sc = __expf(Zbuf[8192 + w * 16 + r] - mf);
        lf += Zbuf[8320 + w * 16 + r] * sc;
        z  += Zbuf[(w * 16 + r) * 64 + d] * sc;
      }
      Zout[((size_t)b * S_LEN + s0 + r) * DIM + d] = z / lf;
    }
  }
}

extern "C" void kernel_launch(void* const* d_in, const int* in_sizes, int n_in,
                              void* d_out, int out_size, void* d_ws, size_t ws_size,
                              hipStream_t stream) {
  const float* Q   = (const float*)d_in[0];
  const float* K   = (const float*)d_in[1];
  const float* V   = (const float*)d_in[2];
  const float* rel = (const float*)d_in[3];
  // d_in[4] = segment_ids (unused, segmented=False)

  u16* KF = (u16*)d_ws;                                   // [B][276][2][512] bf16
  u16* VF = KF + (size_t)BATCH * NKT * 2 * 512;           // [B][64][2][4][512] bf16
  float* wsZ = (float*)(VF + (size_t)BATCH * 64 * 2 * 4 * 512);  // 2MB scratch Z

  float* energy = (float*)d_out;                          // [B][S][S]
  float* Zout   = energy + (size_t)BATCH * S_LEN * S_LEN; // [B][S][64]

  prep_k2<<<dim3(NKT, BATCH), 128, 0, stream>>>(K, rel, KF);
  prep_v2<<<dim3(S_LEN / 64, BATCH), 256, 0, stream>>>(V, VF);

  const dim3 g(BATCH * (S_LEN / 16));
  // Decision probe: store path deleted, x3 reps (lands in rocprof top-5)
  attn_main<1><<<g, 512, 0, stream>>>(Q, KF, VF, wsZ, wsZ, 3);
  // Real kernel (R20-identical), writes d_out
  attn_main<0><<<g, 512, 0, stream>>>(Q, KF, VF, energy, Zout, 1);
}

// Round 22
// 52.722 us; speedup vs baseline: 2.1553x; 2.1553x over previous
//
#include <hip/hip_runtime.h>

#define S_LEN 4096
#define BATCH 2
#define DIM 64
#define RAD 128
#define NPOS 257
#define KEXT 4416              // 4096 + 5*64 (rel rows padded); KEXT/16 = 276 tiles
#define NKT 276                // K fragment tiles per batch
#define QREL_STR 260
#define PSTR 72                // P LDS row stride in u16 (144B, 16B-aligned)

typedef short s16x8 __attribute__((ext_vector_type(8)));
typedef short s16x4 __attribute__((ext_vector_type(4)));
typedef float f32x4 __attribute__((ext_vector_type(4)));
typedef unsigned short u16;
typedef unsigned int u32;

__device__ __forceinline__ u16 f2bf(float f) {
  union { float f; u32 u; } v; v.f = f;
  u32 u = v.u;
  return (u16)((u + 0x7FFFu + ((u >> 16) & 1u)) >> 16);  // RNE
}
__device__ __forceinline__ float bf2f(u16 h) {
  union { u32 u; float f; } v; v.u = ((u32)h) << 16; return v.f;
}

// KF[b][Ti][ks][lane][j]: fragment-contiguous K (+rel rows appended).
__global__ void prep_k2(const float* __restrict__ K, const float* __restrict__ rel,
                        u16* __restrict__ KF) {
  __shared__ float lds[16][65];
  const int b = blockIdx.y;
  const int Ti = blockIdx.x;           // 0..275
  const int tid = threadIdx.x;         // 128
  for (int i = tid; i < 1024; i += 128) {
    const int r = i >> 6, c = i & 63;
    const int t = Ti * 16 + r;
    float v = 0.f;
    if (t < S_LEN) v = K[((size_t)b * S_LEN + t) * DIM + c];
    else if (t - S_LEN < NPOS) v = rel[(size_t)(t - S_LEN) * DIM + c];
    lds[r][c] = v;
  }
  __syncthreads();
  const int ks = tid >> 6, lane = tid & 63;
  const int l15 = lane & 15, q4 = lane >> 4;
  s16x8 o;
#pragma unroll
  for (int j = 0; j < 8; ++j) o[j] = (short)f2bf(lds[l15][ks * 32 + q4 * 8 + j]);
  *reinterpret_cast<s16x8*>(KF + (((size_t)(b * NKT + Ti)) * 2 + ks) * 512 + lane * 8) = o;
}

// VF[b][T6][ks][dn][lane][j]: fragment-contiguous V.
__global__ void prep_v2(const float* __restrict__ V, u16* __restrict__ VF) {
  __shared__ float lds[64][65];
  const int b = blockIdx.y;
  const int T6 = blockIdx.x;           // 0..63
  const int tid = threadIdx.x;         // 256
  for (int i = tid; i < 4096; i += 256) {
    const int r = i >> 6, c = i & 63;
    lds[r][c] = V[((size_t)b * S_LEN + T6 * 64 + r) * DIM + c];
  }
  __syncthreads();
  const int dn = tid >> 6, lane = tid & 63;
  const int l15 = lane & 15, q4 = lane >> 4;
#pragma unroll
  for (int ks = 0; ks < 2; ++ks) {
    s16x8 o;
#pragma unroll
    for (int j = 0; j < 8; ++j) o[j] = (short)f2bf(lds[ks * 32 + q4 * 8 + j][dn * 16 + l15]);
    *reinterpret_cast<s16x8*>(
        VF + ((((size_t)(b * 64 + T6)) * 2 + ks) * 4 + dn) * 512 + lane * 8) = o;
  }
}

// R16/R20 structure + DEFERRED full-line stores: tile i's [transposed LDS
// read + 4 nt stores] execute at the top of iter i+1, AFTER i+1's KF/VF
// loads issue. Stores are then the NEWEST vmem ops, so the QK load-wait is
// a counted vmcnt that leaves them outstanding -> each store batch drains
// under a full iteration of compute (R21 probe: compute 21.5us, store
// exposure 23.5us, zero overlap; this is the decoupling fix).
// Single esw buffer is safe: deferred ds_read precedes the new stage-write
// in program order (same LDS addresses -> order preserved).
// Swapped-operand MFMAs keep q == l15 lane-local:
//   QK^T: mfma(kf, qf) -> D[t=q4*4+reg][q=l15]
//   PV:   mfma(vf, pf) -> D[d=dn*16+q4*4+reg][q=l15]
__launch_bounds__(512, 4)
__global__ void attn_main(const float* __restrict__ Q,
                          const u16* __restrict__ KF,
                          const u16* __restrict__ VF,
                          float* __restrict__ energy,
                          float* __restrict__ Zout) {
  // carve: qrel_bf[16*260] u16 (8320B) | estage 8x4096B (32768B) | plds (18432B)
  __shared__ __align__(16) char smem[8320 + 32768 + 18432];
  u16* qrel_bf = (u16*)smem;
  char* estage = smem + 8320;
  u16* plds = (u16*)(smem + 8320 + 32768);
  float* Zbuf = (float*)estage;        // epilogue overlay

  const int tid = threadIdx.x;
  const int lane = tid & 63;
  const int wid = tid >> 6;            // 0..7
  const int l15 = lane & 15, q4 = lane >> 4;
  const int bx = blockIdx.x;
  const int b = bx >> 8;
  const int s0 = (bx & 255) * 16;

  const u16* KFB = KF + (size_t)b * NKT * 2 * 512;
  const u16* VFB = VF + (size_t)b * 64 * 2 * 4 * 512;
  const int lane8 = lane * 8;
  char* esw = estage + wid * 4096;

  // ---- Q B-fragments (row s0+l15) ----
  s16x8 qfrag[2];
  {
    const float* qp = Q + ((size_t)b * S_LEN + s0 + l15) * DIM + q4 * 8;
#pragma unroll
    for (int ks = 0; ks < 2; ++ks) {
      f32x4 a = *reinterpret_cast<const f32x4*>(qp + ks * 32);
      f32x4 c = *reinterpret_cast<const f32x4*>(qp + ks * 32 + 4);
      s16x8 f;
#pragma unroll
      for (int j = 0; j < 4; ++j) { f[j] = (short)f2bf(a[j]); f[4 + j] = (short)f2bf(c[j]); }
      qfrag[ks] = f;
    }
  }

  // ---- prologue: Q_rel[p][q] via mfma(rel_frag, q); waves 0..4 ----
  for (int pt = wid; pt < 5; pt += 8) {
    f32x4 acc[4] = {};
#pragma unroll
    for (int ks = 0; ks < 2; ++ks)
#pragma unroll
      for (int nf = 0; nf < 4; ++nf) {
        s16x8 kf = *reinterpret_cast<const s16x8*>(
            KFB + ((size_t)(256 + pt * 4 + nf) * 2 + ks) * 512 + lane8);
        acc[nf] = __builtin_amdgcn_mfma_f32_16x16x32_bf16(kf, qfrag[ks], acc[nf], 0, 0, 0);
      }
#pragma unroll
    for (int nf = 0; nf < 4; ++nf)
#pragma unroll
      for (int reg = 0; reg < 4; ++reg) {
        int p = pt * 64 + nf * 16 + q4 * 4 + reg;
        if (p < NPOS) qrel_bf[l15 * QREL_STR + p] = f2bf(acc[nf][reg]);
      }
  }
  __syncthreads();

  // per-row clamped-rel constants, pre-scaled by 1/8
  const float c8lo = bf2f(qrel_bf[l15 * QREL_STR + 0]) * 0.125f;
  const float c8hi = bf2f(qrel_bf[l15 * QREL_STR + 256]) * 0.125f;

  // ---- main loop: 8 t-tiles of 64 per wave, barrier-free ----
  const int qglob = s0 + l15;
  const int qoff = l15 * QREL_STR + RAD;
  u16* pw = plds + wid * 16 * PSTR;
  float* eblk = energy + ((size_t)b * S_LEN + s0) * S_LEN;
  const int hi = lane >> 4, m16 = lane & 15;

  float mprev = -INFINITY, lsum = 0.f;
  f32x4 zacc[4] = {};

  for (int it = 0; it < 8; ++it) {
    const int t0 = wid * 512 + it * 64;
    const int ti4 = t0 >> 4;
    const int t6 = t0 >> 6;

    // KF/VF loads issue FIRST (oldest vmem ops of this iter)
    s16x8 kf[2][4], vf[2][4];
#pragma unroll
    for (int ks = 0; ks < 2; ++ks)
#pragma unroll
      for (int nf = 0; nf < 4; ++nf) {
        kf[ks][nf] = *reinterpret_cast<const s16x8*>(
            KFB + ((size_t)(ti4 + nf) * 2 + ks) * 512 + lane8);
        vf[ks][nf] = *reinterpret_cast<const s16x8*>(
            VFB + (((size_t)t6 * 2 + ks) * 4 + nf) * 512 + lane8);
      }

    // DEFERRED full-line store of the PREVIOUS tile (newest vmem ops ->
    // the QK load-wait leaves them outstanding; they drain under compute)
    if (it > 0) {
      const int tp = t0 - 64;
#pragma unroll
      for (int j = 0; j < 4; ++j) {
        const int r = j * 4 + hi;
        int off = (j << 10) + (hi << 8) + (m16 << 4);
        off ^= (r & 7) << 4;
        f32x4 v = *reinterpret_cast<const f32x4*>(esw + off);
        __builtin_nontemporal_store(
            v, reinterpret_cast<f32x4*>(eblk + (size_t)r * S_LEN + tp + m16 * 4));
      }
    }

    // QK^T
    f32x4 acc[4] = {};
#pragma unroll
    for (int ks = 0; ks < 2; ++ks)
#pragma unroll
      for (int nf = 0; nf < 4; ++nf)
        acc[nf] = __builtin_amdgcn_mfma_f32_16x16x32_bf16(kf[ks][nf], qfrag[ks], acc[nf], 0, 0, 0);

    // rel shift + scale (band-split), lane max
    float mloc = -INFINITY;
    if (t0 >= s0 + 143) {
#pragma unroll
      for (int nf = 0; nf < 4; ++nf)
#pragma unroll
        for (int reg = 0; reg < 4; ++reg) {
          float e = fmaf(acc[nf][reg], 0.125f, c8hi);
          acc[nf][reg] = e;
          mloc = fmaxf(mloc, e);
        }
    } else if (t0 <= s0 - 191) {
#pragma unroll
      for (int nf = 0; nf < 4; ++nf)
#pragma unroll
        for (int reg = 0; reg < 4; ++reg) {
          float e = fmaf(acc[nf][reg], 0.125f, c8lo);
          acc[nf][reg] = e;
          mloc = fmaxf(mloc, e);
        }
    } else {
#pragma unroll
      for (int nf = 0; nf < 4; ++nf) {
        const int tb = t0 + nf * 16 + q4 * 4;
#pragma unroll
        for (int reg = 0; reg < 4; ++reg) {
          int p = tb + reg - qglob;
          p = (p < -RAD) ? -RAD : (p > RAD ? RAD : p);
          float e = (acc[nf][reg] + bf2f(qrel_bf[qoff + p])) * 0.125f;
          acc[nf][reg] = e;
          mloc = fmaxf(mloc, e);
        }
      }
    }

    // stage e-tile into private LDS (swizzled; after the deferred ds_read
    // of the previous tile in program order -> no clobber)
#pragma unroll
    for (int nf = 0; nf < 4; ++nf) {
      int off = ((l15 >> 2) << 10) + ((l15 & 3) << 8) + ((nf * 4 + q4) << 4);
      off ^= (l15 & 7) << 4;
      *reinterpret_cast<f32x4*>(esw + off) = acc[nf];
    }

    // online softmax; skip rescale when max didn't grow
    if (__all(mloc <= mprev)) {
    } else {
      mloc = fmaxf(mloc, __shfl_xor(mloc, 16));
      mloc = fmaxf(mloc, __shfl_xor(mloc, 32));
      const float mn = fmaxf(mprev, mloc);
      const float alpha = __expf(mprev - mn);
      mprev = mn;
      lsum *= alpha;
#pragma unroll
      for (int dn = 0; dn < 4; ++dn) zacc[dn] *= alpha;
    }

    float rs = 0.f;
#pragma unroll
    for (int nf = 0; nf < 4; ++nf) {
      float p0 = __expf(acc[nf][0] - mprev);
      float p1 = __expf(acc[nf][1] - mprev);
      float p2 = __expf(acc[nf][2] - mprev);
      float p3 = __expf(acc[nf][3] - mprev);
      rs += (p0 + p1) + (p2 + p3);
      union { u32 w[2]; s16x4 v; } pk;
      asm("v_cvt_pk_bf16_f32 %0, %1, %2" : "=v"(pk.w[0]) : "v"(p0), "v"(p1));
      asm("v_cvt_pk_bf16_f32 %0, %1, %2" : "=v"(pk.w[1]) : "v"(p2), "v"(p3));
      *reinterpret_cast<s16x4*>(pw + l15 * PSTR + nf * 16 + q4 * 4) = pk.v;
    }
    rs += __shfl_xor(rs, 16);
    rs += __shfl_xor(rs, 32);
    lsum += rs;

    // PV: mfma(vf, pf) -> zacc[dn] holds Z[d=dn*16+q4*4+reg][q=l15]
#pragma unroll
    for (int ks = 0; ks < 2; ++ks) {
      s16x8 pf = *reinterpret_cast<const s16x8*>(pw + l15 * PSTR + ks * 32 + q4 * 8);
#pragma unroll
      for (int dn = 0; dn < 4; ++dn)
        zacc[dn] = __builtin_amdgcn_mfma_f32_16x16x32_bf16(vf[ks][dn], pf, zacc[dn], 0, 0, 0);
    }
  }

  // final deferred store (tile 7)
  {
    const int tp = wid * 512 + 7 * 64;
#pragma unroll
    for (int j = 0; j < 4; ++j) {
      const int r = j * 4 + hi;
      int off = (j << 10) + (hi << 8) + (m16 << 4);
      off ^= (r & 7) << 4;
      f32x4 v = *reinterpret_cast<const f32x4*>(esw + off);
      __builtin_nontemporal_store(
          v, reinterpret_cast<f32x4*>(eblk + (size_t)r * S_LEN + tp + m16 * 4));
    }
  }

  // ---- cross-wave combine (overlay Zbuf on estage+plds) ----
  __syncthreads();
#pragma unroll
  for (int dn = 0; dn < 4; ++dn)
    *reinterpret_cast<f32x4*>(&Zbuf[(wid * 16 + l15) * 64 + dn * 16 + q4 * 4]) = zacc[dn];
  if (q4 == 0) {
    Zbuf[8192 + wid * 16 + l15] = mprev;
    Zbuf[8320 + wid * 16 + l15] = lsum;
  }
  __syncthreads();

  {
    const int r0 = tid >> 6, d = tid & 63;
#pragma unroll
    for (int rr = 0; rr < 2; ++rr) {
      const int r = rr * 8 + r0;
      float mf = -INFINITY;
#pragma unroll
      for (int w = 0; w < 8; ++w) mf = fmaxf(mf, Zbuf[8192 + w * 16 + r]);
      float lf = 0.f, z = 0.f;
#pragma unroll
      for (int w = 0; w < 8; ++w) {
        const float sc = __expf(Zbuf[8192 + w * 16 + r] - mf);
        lf += Zbuf[8320 + w * 16 + r] * sc;
        z  += Zbuf[(w * 16 + r) * 64 + d] * sc;
      }
      Zout[((size_t)b * S_LEN + s0 + r) * DIM + d] = z / lf;
    }
  }
}

extern "C" void kernel_launch(void* const* d_in, const int* in_sizes, int n_in,
                              void* d_out, int out_size, void* d_ws, size_t ws_size,
                              hipStream_t stream) {
  const float* Q   = (const float*)d_in[0];
  const float* K   = (const float*)d_in[1];
  const float* V   = (const float*)d_in[2];
  const float* rel = (const float*)d_in[3];
  // d_in[4] = segment_ids (unused, segmented=False)

  u16* KF = (u16*)d_ws;                                   // [B][276][2][512] bf16
  u16* VF = KF + (size_t)BATCH * NKT * 2 * 512;           // [B][64][2][4][512] bf16

  float* energy = (float*)d_out;                          // [B][S][S]
  float* Zout   = energy + (size_t)BATCH * S_LEN * S_LEN; // [B][S][64]

  prep_k2<<<dim3(NKT, BATCH), 128, 0, stream>>>(K, rel, KF);
  prep_v2<<<dim3(S_LEN / 64, BATCH), 256, 0, stream>>>(V, VF);
  attn_main<<<dim3(BATCH * (S_LEN / 16)), 512, 0, stream>>>(Q, KF, VF, energy, Zout);
}

// Round 23
// 49.002 us; speedup vs baseline: 2.3190x; 1.0759x over previous
//
#include <hip/hip_runtime.h>

#define S_LEN 4096
#define BATCH 2
#define DIM 64
#define RAD 128
#define NPOS 257
#define KEXT 4416              // 4096 + 5*64 (rel rows padded); KEXT/16 = 276 tiles
#define NKT 276                // K fragment tiles per batch
#define QREL_STR 260
#define PSTR 72                // P LDS row stride in u16 (144B, 16B-aligned)

typedef short s16x8 __attribute__((ext_vector_type(8)));
typedef short s16x4 __attribute__((ext_vector_type(4)));
typedef float f32x4 __attribute__((ext_vector_type(4)));
typedef unsigned short u16;
typedef unsigned int u32;

__device__ __forceinline__ u16 f2bf(float f) {
  union { float f; u32 u; } v; v.f = f;
  u32 u = v.u;
  return (u16)((u + 0x7FFFu + ((u >> 16) & 1u)) >> 16);  // RNE
}
__device__ __forceinline__ float bf2f(u16 h) {
  union { u32 u; float f; } v; v.u = ((u32)h) << 16; return v.f;
}

// KF[b][Ti][ks][lane][j]: fragment-contiguous K (+rel rows appended).
__global__ void prep_k2(const float* __restrict__ K, const float* __restrict__ rel,
                        u16* __restrict__ KF) {
  __shared__ float lds[16][65];
  const int b = blockIdx.y;
  const int Ti = blockIdx.x;           // 0..275
  const int tid = threadIdx.x;         // 128
  for (int i = tid; i < 1024; i += 128) {
    const int r = i >> 6, c = i & 63;
    const int t = Ti * 16 + r;
    float v = 0.f;
    if (t < S_LEN) v = K[((size_t)b * S_LEN + t) * DIM + c];
    else if (t - S_LEN < NPOS) v = rel[(size_t)(t - S_LEN) * DIM + c];
    lds[r][c] = v;
  }
  __syncthreads();
  const int ks = tid >> 6, lane = tid & 63;
  const int l15 = lane & 15, q4 = lane >> 4;
  s16x8 o;
#pragma unroll
  for (int j = 0; j < 8; ++j) o[j] = (short)f2bf(lds[l15][ks * 32 + q4 * 8 + j]);
  *reinterpret_cast<s16x8*>(KF + (((size_t)(b * NKT + Ti)) * 2 + ks) * 512 + lane * 8) = o;
}

// VF[b][T6][ks][dn][lane][j]: fragment-contiguous V.
__global__ void prep_v2(const float* __restrict__ V, u16* __restrict__ VF) {
  __shared__ float lds[64][65];
  const int b = blockIdx.y;
  const int T6 = blockIdx.x;           // 0..63
  const int tid = threadIdx.x;         // 256
  for (int i = tid; i < 4096; i += 256) {
    const int r = i >> 6, c = i & 63;
    lds[r][c] = V[((size_t)b * S_LEN + T6 * 64 + r) * DIM + c];
  }
  __syncthreads();
  const int dn = tid >> 6, lane = tid & 63;
  const int l15 = lane & 15, q4 = lane >> 4;
#pragma unroll
  for (int ks = 0; ks < 2; ++ks) {
    s16x8 o;
#pragma unroll
    for (int j = 0; j < 8; ++j) o[j] = (short)f2bf(lds[ks * 32 + q4 * 8 + j][dn * 16 + l15]);
    *reinterpret_cast<s16x8*>(
        VF + ((((size_t)(b * 64 + T6)) * 2 + ks) * 4 + dn) * 512 + lane * 8) = o;
  }
}

// R16/R20 (proven 49.2-49.3us, best verified): fragment-contiguous KF/VF
// loads (1KB coalesced wave-bursts); P via per-wave plds; energy staged in a
// private swizzled LDS tile and stored FULL-LINE (4 rows x 256B contiguous
// per instr). Barrier-free main loop.
// Floor accounting (R21 probe): compute 21.5us (chain-bound, 4 waves/SIMD
// VGPR cap) + store exposure 23.5us (134MB @ 5.7TB/s, queue-bound) ~= 45us
// attn, additive; all overlap levers tested null (R11/R13/R14/R15/R17/R22).
// Swapped-operand MFMAs keep q == l15 lane-local:
//   QK^T: mfma(kf, qf) -> D[t=q4*4+reg][q=l15]
//   PV:   mfma(vf, pf) -> D[d=dn*16+q4*4+reg][q=l15]
__launch_bounds__(512, 4)
__global__ void attn_main(const float* __restrict__ Q,
                          const u16* __restrict__ KF,
                          const u16* __restrict__ VF,
                          float* __restrict__ energy,
                          float* __restrict__ Zout) {
  // carve: qrel_bf[16*260] u16 (8320B) | estage 8x4096B (32768B) | plds (18432B)
  __shared__ __align__(16) char smem[8320 + 32768 + 18432];
  u16* qrel_bf = (u16*)smem;
  char* estage = smem + 8320;
  u16* plds = (u16*)(smem + 8320 + 32768);
  float* Zbuf = (float*)estage;        // epilogue overlay

  const int tid = threadIdx.x;
  const int lane = tid & 63;
  const int wid = tid >> 6;            // 0..7
  const int l15 = lane & 15, q4 = lane >> 4;
  const int bx = blockIdx.x;
  const int b = bx >> 8;
  const int s0 = (bx & 255) * 16;

  const u16* KFB = KF + (size_t)b * NKT * 2 * 512;
  const u16* VFB = VF + (size_t)b * 64 * 2 * 4 * 512;
  const int lane8 = lane * 8;
  char* esw = estage + wid * 4096;

  // ---- Q B-fragments (row s0+l15) ----
  s16x8 qfrag[2];
  {
    const float* qp = Q + ((size_t)b * S_LEN + s0 + l15) * DIM + q4 * 8;
#pragma unroll
    for (int ks = 0; ks < 2; ++ks) {
      f32x4 a = *reinterpret_cast<const f32x4*>(qp + ks * 32);
      f32x4 c = *reinterpret_cast<const f32x4*>(qp + ks * 32 + 4);
      s16x8 f;
#pragma unroll
      for (int j = 0; j < 4; ++j) { f[j] = (short)f2bf(a[j]); f[4 + j] = (short)f2bf(c[j]); }
      qfrag[ks] = f;
    }
  }

  // ---- prologue: Q_rel[p][q] via mfma(rel_frag, q); waves 0..4 ----
  for (int pt = wid; pt < 5; pt += 8) {
    f32x4 acc[4] = {};
#pragma unroll
    for (int ks = 0; ks < 2; ++ks)
#pragma unroll
      for (int nf = 0; nf < 4; ++nf) {
        s16x8 kf = *reinterpret_cast<const s16x8*>(
            KFB + ((size_t)(256 + pt * 4 + nf) * 2 + ks) * 512 + lane8);
        acc[nf] = __builtin_amdgcn_mfma_f32_16x16x32_bf16(kf, qfrag[ks], acc[nf], 0, 0, 0);
      }
#pragma unroll
    for (int nf = 0; nf < 4; ++nf)
#pragma unroll
      for (int reg = 0; reg < 4; ++reg) {
        int p = pt * 64 + nf * 16 + q4 * 4 + reg;
        if (p < NPOS) qrel_bf[l15 * QREL_STR + p] = f2bf(acc[nf][reg]);
      }
  }
  __syncthreads();

  // per-row clamped-rel constants, pre-scaled by 1/8
  const float c8lo = bf2f(qrel_bf[l15 * QREL_STR + 0]) * 0.125f;
  const float c8hi = bf2f(qrel_bf[l15 * QREL_STR + 256]) * 0.125f;

  // ---- main loop: 8 t-tiles of 64 per wave, barrier-free ----
  const int qglob = s0 + l15;
  const int qoff = l15 * QREL_STR + RAD;
  u16* pw = plds + wid * 16 * PSTR;
  float* eblk = energy + ((size_t)b * S_LEN + s0) * S_LEN;
  const int hi = lane >> 4, m16 = lane & 15;

  float mprev = -INFINITY, lsum = 0.f;
  f32x4 zacc[4] = {};

  for (int it = 0; it < 8; ++it) {
    const int t0 = wid * 512 + it * 64;
    const int ti4 = t0 >> 4;
    const int t6 = t0 >> 6;

    // QK^T from fragment-contiguous KF
    f32x4 acc[4] = {};
#pragma unroll
    for (int ks = 0; ks < 2; ++ks)
#pragma unroll
      for (int nf = 0; nf < 4; ++nf) {
        s16x8 kf = *reinterpret_cast<const s16x8*>(
            KFB + ((size_t)(ti4 + nf) * 2 + ks) * 512 + lane8);
        acc[nf] = __builtin_amdgcn_mfma_f32_16x16x32_bf16(kf, qfrag[ks], acc[nf], 0, 0, 0);
      }

    // V fragments issued early; latency hides under softmax
    s16x8 vf[2][4];
#pragma unroll
    for (int ks = 0; ks < 2; ++ks)
#pragma unroll
      for (int dn = 0; dn < 4; ++dn)
        vf[ks][dn] = *reinterpret_cast<const s16x8*>(
            VFB + (((size_t)t6 * 2 + ks) * 4 + dn) * 512 + lane8);

    // rel shift + scale (band-split), lane max
    float mloc = -INFINITY;
    if (t0 >= s0 + 143) {
#pragma unroll
      for (int nf = 0; nf < 4; ++nf)
#pragma unroll
        for (int reg = 0; reg < 4; ++reg) {
          float e = fmaf(acc[nf][reg], 0.125f, c8hi);
          acc[nf][reg] = e;
          mloc = fmaxf(mloc, e);
        }
    } else if (t0 <= s0 - 191) {
#pragma unroll
      for (int nf = 0; nf < 4; ++nf)
#pragma unroll
        for (int reg = 0; reg < 4; ++reg) {
          float e = fmaf(acc[nf][reg], 0.125f, c8lo);
          acc[nf][reg] = e;
          mloc = fmaxf(mloc, e);
        }
    } else {
#pragma unroll
      for (int nf = 0; nf < 4; ++nf) {
        const int tb = t0 + nf * 16 + q4 * 4;
#pragma unroll
        for (int reg = 0; reg < 4; ++reg) {
          int p = tb + reg - qglob;
          p = (p < -RAD) ? -RAD : (p > RAD ? RAD : p);
          float e = (acc[nf][reg] + bf2f(qrel_bf[qoff + p])) * 0.125f;
          acc[nf][reg] = e;
          mloc = fmaxf(mloc, e);
        }
      }
    }

    // stage e-tile into private LDS (swizzled; read side applies same XOR)
#pragma unroll
    for (int nf = 0; nf < 4; ++nf) {
      int off = ((l15 >> 2) << 10) + ((l15 & 3) << 8) + ((nf * 4 + q4) << 4);
      off ^= (l15 & 7) << 4;
      *reinterpret_cast<f32x4*>(esw + off) = acc[nf];
    }

    // online softmax; skip rescale when max didn't grow
    if (__all(mloc <= mprev)) {
    } else {
      mloc = fmaxf(mloc, __shfl_xor(mloc, 16));
      mloc = fmaxf(mloc, __shfl_xor(mloc, 32));
      const float mn = fmaxf(mprev, mloc);
      const float alpha = __expf(mprev - mn);
      mprev = mn;
      lsum *= alpha;
#pragma unroll
      for (int dn = 0; dn < 4; ++dn) zacc[dn] *= alpha;
    }

    float rs = 0.f;
#pragma unroll
    for (int nf = 0; nf < 4; ++nf) {
      float p0 = __expf(acc[nf][0] - mprev);
      float p1 = __expf(acc[nf][1] - mprev);
      float p2 = __expf(acc[nf][2] - mprev);
      float p3 = __expf(acc[nf][3] - mprev);
      rs += (p0 + p1) + (p2 + p3);
      union { u32 w[2]; s16x4 v; } pk;
      asm("v_cvt_pk_bf16_f32 %0, %1, %2" : "=v"(pk.w[0]) : "v"(p0), "v"(p1));
      asm("v_cvt_pk_bf16_f32 %0, %1, %2" : "=v"(pk.w[1]) : "v"(p2), "v"(p3));
      *reinterpret_cast<s16x4*>(pw + l15 * PSTR + nf * 16 + q4 * 4) = pk.v;
    }
    rs += __shfl_xor(rs, 16);
    rs += __shfl_xor(rs, 32);
    lsum += rs;

    // PV: mfma(vf, pf) -> zacc[dn] holds Z[d=dn*16+q4*4+reg][q=l15]
#pragma unroll
    for (int ks = 0; ks < 2; ++ks) {
      s16x8 pf = *reinterpret_cast<const s16x8*>(pw + l15 * PSTR + ks * 32 + q4 * 8);
#pragma unroll
      for (int dn = 0; dn < 4; ++dn)
        zacc[dn] = __builtin_amdgcn_mfma_f32_16x16x32_bf16(vf[ks][dn], pf, zacc[dn], 0, 0, 0);
    }

    // FULL-LINE energy store: read e-tile transposed from LDS (writes above
    // drained under softmax+PV), store 4 rows x 256B contiguous per instr.
#pragma unroll
    for (int j = 0; j < 4; ++j) {
      const int r = j * 4 + hi;
      int off = (j << 10) + (hi << 8) + (m16 << 4);
      off ^= (r & 7) << 4;
      f32x4 v = *reinterpret_cast<const f32x4*>(esw + off);
      __builtin_nontemporal_store(
          v, reinterpret_cast<f32x4*>(eblk + (size_t)r * S_LEN + t0 + m16 * 4));
    }
  }

  // ---- cross-wave combine (overlay Zbuf on estage+plds) ----
  __syncthreads();
#pragma unroll
  for (int dn = 0; dn < 4; ++dn)
    *reinterpret_cast<f32x4*>(&Zbuf[(wid * 16 + l15) * 64 + dn * 16 + q4 * 4]) = zacc[dn];
  if (q4 == 0) {
    Zbuf[8192 + wid * 16 + l15] = mprev;
    Zbuf[8320 + wid * 16 + l15] = lsum;
  }
  __syncthreads();

  {
    const int r0 = tid >> 6, d = tid & 63;
#pragma unroll
    for (int rr = 0; rr < 2; ++rr) {
      const int r = rr * 8 + r0;
      float mf = -INFINITY;
#pragma unroll
      for (int w = 0; w < 8; ++w) mf = fmaxf(mf, Zbuf[8192 + w * 16 + r]);
      float lf = 0.f, z = 0.f;
#pragma unroll
      for (int w = 0; w < 8; ++w) {
        const float sc = __expf(Zbuf[8192 + w * 16 + r] - mf);
        lf += Zbuf[8320 + w * 16 + r] * sc;
        z  += Zbuf[(w * 16 + r) * 64 + d] * sc;
      }
      Zout[((size_t)b * S_LEN + s0 + r) * DIM + d] = z / lf;
    }
  }
}

extern "C" void kernel_launch(void* const* d_in, const int* in_sizes, int n_in,
                              void* d_out, int out_size, void* d_ws, size_t ws_size,
                              hipStream_t stream) {
  const float* Q   = (const float*)d_in[0];
  const float* K   = (const float*)d_in[1];
  const float* V   = (const float*)d_in[2];
  const float* rel = (const float*)d_in[3];
  // d_in[4] = segment_ids (unused, segmented=False)

  u16* KF = (u16*)d_ws;                                   // [B][276][2][512] bf16
  u16* VF = KF + (size_t)BATCH * NKT * 2 * 512;           // [B][64][2][4][512] bf16

  float* energy = (float*)d_out;                          // [B][S][S]
  float* Zout   = energy + (size_t)BATCH * S_LEN * S_LEN; // [B][S][64]

  prep_k2<<<dim3(NKT, BATCH), 128, 0, stream>>>(K, rel, KF);
  prep_v2<<<dim3(S_LEN / 64, BATCH), 256, 0, stream>>>(V, VF);
  attn_main<<<dim3(BATCH * (S_LEN / 16)), 512, 0, stream>>>(Q, KF, VF, energy, Zout);
}